// Round 1
// baseline (211.925 us; speedup 1.0000x reference)
//
#include <hip/hip_runtime.h>
#include <math.h>

// Problem constants (from reference): B=65536 rows, D=384, subject ids in [0,1024),
// MAX_PAIRS=50, TEMPERATURE=0.5, EPS=1e-12.
#define NSUB 1024
#define CAP 128      // per-subject stored indices; consumed ranks are provably < 52
#define MAXP 50
#define TEMP_INV 2.0f
#define EPSN 1e-12f

// K1: histogram counts per subject + unordered scatter of element indices into
// per-subject buckets. Detects int32 vs int64 id storage per-block: in int64
// little-endian storage every odd int32 word is a zero high-word (ids < 1024);
// in int32 storage odd words are real ids (nonzero w.p. 1-2^-~1280 per block).
__global__ void k_hist(const int* __restrict__ sid32, int B,
                       int* __restrict__ cnt, int* __restrict__ idxbuf) {
    int tid = threadIdx.x;
    int i = blockIdx.x * blockDim.x + tid;
    int w = (i < B) ? sid32[i] : 0;
    int odd_nz = ((tid & 1) && (i < B) && (w != 0)) ? 1 : 0;
    int is32 = __syncthreads_or(odd_nz);   // all threads reach this
    if (i >= B) return;
    int s = is32 ? w : sid32[2 * i];       // int64 mode: low word of element i
    if ((unsigned)s < (unsigned)NSUB) {
        int slot = atomicAdd(&cnt[s], 1);
        if (slot < CAP) idxbuf[s * CAP + slot] = i;
    }
}

// K2: single block. (a) counts -> LDS; (b) thread 0 replays _build_pair_indices
// in (subject, rank) space exactly (only consults counts, like the Python code
// only consults len(idx_by[s])); (c) waves rank-select (subject,rank)->row index
// from the unordered buckets; (d) waves compute per-pair cosine-sim + BCE.
__global__ __launch_bounds__(1024)
void k_main(const float* __restrict__ X, int D,
            const int* __restrict__ cnt_g, const int* __restrict__ idxbuf,
            float* __restrict__ out) {
    __shared__ int ls_cnt[NSUB];
    __shared__ short ps_s[MAXP], ps_a[MAXP], ps_b[MAXP];
    __shared__ short ng_s[MAXP], ng_a[MAXP], ng_o[MAXP], ng_b[MAXP];
    __shared__ int res_i[2 * MAXP], res_j[2 * MAXP];
    __shared__ int sh_npos, sh_ntot;
    __shared__ float wsum[16];

    int tid = threadIdx.x;
    for (int k = tid; k < NSUB; k += blockDim.x) ls_cnt[k] = cnt_g[k];
    __syncthreads();

    if (tid == 0) {
        int n_pos = 0, n_neg = 0;
        for (int s = 0; s < NSUB; ++s) {
            int m = ls_cnt[s];
            if (m == 0) continue;                 // s not in uniq
            if (m >= 2 && n_pos < MAXP) {         // pos: a<b lexicographic, append while <50
                for (int a = 0; a < m && n_pos < MAXP; ++a)
                    for (int b = a + 1; b < m && n_pos < MAXP; ++b) {
                        ps_s[n_pos] = (short)s; ps_a[n_pos] = (short)a; ps_b[n_pos] = (short)b;
                        ++n_pos;
                    }
            }
            for (int o = 0; o < NSUB; ++o) {      // neg: o over uniq, skip o==s, break when full
                if (o == s) continue;
                int n = ls_cnt[o];
                if (n == 0) continue;             // not in uniq
                if (n_neg >= MAXP) break;
                for (int a = 0; a < m && n_neg < MAXP; ++a)
                    for (int b = 0; b < n && n_neg < MAXP; ++b) {
                        ng_s[n_neg] = (short)s; ng_a[n_neg] = (short)a;
                        ng_o[n_neg] = (short)o; ng_b[n_neg] = (short)b;
                        ++n_neg;
                    }
            }
            if (n_pos >= MAXP && n_neg >= MAXP) break;
        }
        sh_npos = n_pos; sh_ntot = n_pos + n_neg;
    }
    __syncthreads();

    int n_pos = sh_npos, n_tot = sh_ntot;
    int wave = tid >> 6, lane = tid & 63;
    int nwaves = blockDim.x >> 6;

    // Resolve (subject, rank) -> global row index. Bucket entries are distinct,
    // so rank(v) = #{e in bucket : e < v} is exact. One wave per item.
    for (int q = wave; q < 2 * n_tot; q += nwaves) {
        int p = q >> 1, isj = q & 1;
        int s, r;
        if (p < n_pos) { s = ps_s[p]; r = isj ? (int)ps_b[p] : (int)ps_a[p]; }
        else {
            int t2 = p - n_pos;
            s = isj ? (int)ng_o[t2] : (int)ng_s[t2];
            r = isj ? (int)ng_b[t2] : (int)ng_a[t2];
        }
        int n = ls_cnt[s]; if (n > CAP) n = CAP;
        const int* L = idxbuf + s * CAP;
        int v0 = (lane < n) ? L[lane] : 0x7fffffff;
        int v1 = (lane + 64 < n) ? L[lane + 64] : 0x7fffffff;
        int r0 = 0, r1 = 0;
        for (int k = 0; k < n; ++k) {
            int e = L[k];                 // wave-uniform broadcast load (L1-hit)
            r0 += (e < v0) ? 1 : 0;
            r1 += (e < v1) ? 1 : 0;
        }
        unsigned long long m0 = __ballot((lane < n) && (r0 == r));
        unsigned long long m1 = __ballot((lane + 64 < n) && (r1 == r));
        int resolved = 0;
        if (m0) resolved = __shfl(v0, (int)(__ffsll(m0) - 1), 64);
        else if (m1) resolved = __shfl(v1, (int)(__ffsll(m1) - 1), 64);
        if (lane == 0) { if (isj) res_j[p] = resolved; else res_i[p] = resolved; }
    }
    __syncthreads();

    // Per-pair cosine sim with the reference's double-normalize-with-eps, then
    // stable BCE-with-logits. One wave per pair; lanes stride over D.
    float acc = 0.0f;
    for (int p = wave; p < n_tot; p += nwaves) {
        const float* xi = X + (size_t)res_i[p] * (size_t)D;
        const float* xj = X + (size_t)res_j[p] * (size_t)D;
        float dij = 0.f, dii = 0.f, djj = 0.f;
        for (int k = lane; k < D; k += 64) {
            float a = xi[k], b = xj[k];
            dij += a * b; dii += a * a; djj += b * b;
        }
        for (int off = 32; off >= 1; off >>= 1) {
            dij += __shfl_xor(dij, off, 64);
            dii += __shfl_xor(dii, off, 64);
            djj += __shfl_xor(djj, off, 64);
        }
        float ni = sqrtf(dii), nj = sqrtf(djj);
        float d1i = fmaxf(ni, EPSN), d1j = fmaxf(nj, EPSN);   // first normalize denom
        float d2i = fmaxf(ni / d1i, EPSN), d2j = fmaxf(nj / d1j, EPSN); // second
        float sim = dij / (d1i * d2i * d1j * d2j) * TEMP_INV;
        float x = (p < n_pos) ? -sim : sim;                   // BCE: softplus(±sim)
        acc += fmaxf(x, 0.f) + log1pf(expf(-fabsf(x)));
    }
    if (lane == 0) wsum[wave] = acc;   // all lanes hold the same reduced values
    __syncthreads();
    if (tid == 0) {
        float tot = 0.f;
        for (int w2 = 0; w2 < nwaves; ++w2) tot += wsum[w2];
        out[0] = (n_tot > 0) ? tot / (float)n_tot : 0.0f;
    }
}

extern "C" void kernel_launch(void* const* d_in, const int* in_sizes, int n_in,
                              void* d_out, int out_size, void* d_ws, size_t ws_size,
                              hipStream_t stream) {
    const float* X = (const float*)d_in[0];
    const int* sid32 = (const int*)d_in[1];   // int32 view; K1 auto-detects int64
    float* out = (float*)d_out;

    int B = in_sizes[1];
    int D = in_sizes[0] / B;

    int* cnt = (int*)d_ws;                          // 1024 * 4 B
    int* idxbuf = (int*)((char*)d_ws + 4096);       // 1024 * 128 * 4 B = 512 KB

    hipMemsetAsync(cnt, 0, NSUB * sizeof(int), stream);
    k_hist<<<(B + 255) / 256, 256, 0, stream>>>(sid32, B, cnt, idxbuf);
    k_main<<<1, 1024, 0, stream>>>(X, D, cnt, idxbuf, out);
}